// Round 2
// baseline (133.799 us; speedup 1.0000x reference)
//
#include <hip/hip_runtime.h>
#include <hip/hip_bf16.h>

typedef __attribute__((ext_vector_type(8))) short bf16x8;
typedef __attribute__((ext_vector_type(4))) float f32x4;

#define N_PTS   16384
#define C_CH    64
#define K_ADJ   17
#define C_OUT   128
#define N_J     16

// bf16 weights, layout [j][o][c] so an A-fragment read is 16B contiguous per lane.
__device__ __hip_bfloat16 g_wb[N_J * C_OUT * C_CH];

__global__ __launch_bounds__(256) void prep_weights_k(const float* __restrict__ w) {
    int idx = blockIdx.x * 256 + threadIdx.x;      // 0 .. 131071 exactly
    int c = idx & 63;
    int o = (idx >> 6) & 127;
    int j = idx >> 13;
    g_wb[idx] = __float2bfloat16(w[(o * C_CH + c) * N_J + j]);
}

// Block: 256 threads = 4 waves. Block tile: 32 tokens x 128 outputs.
// Wave wid: tg = wid&1 (16-token group), oh = wid>>1 (64-output half).
// Lane l owns token (l&15), channels (l>>4)*8 + {0..7} and +32
//   -> exactly the MFMA 16x16x32 B-fragment layout (verified round 1).
// Grid 1024 = 4 blocks/CU -> 16 waves/CU (50% occ), vs 8 before.
__global__ __launch_bounds__(256, 4) void sconv_k(
    const float* __restrict__ x,
    const int*   __restrict__ adj,
    float*       __restrict__ out)
{
    // XCD-aware bijective swizzle (1024 blocks): batch 0 -> XCDs 0..3,
    // batch 1 -> XCDs 4..7, so each XCD's L2 holds one 4 MB x slice.
    const int p    = blockIdx.x;
    const int g8   = p & 7;
    const int b    = g8 >> 2;                      // batch
    const int slot = ((p >> 3) << 2) | (g8 & 3);   // 0..511 within batch

    const int lane = threadIdx.x & 63;
    const int wid  = threadIdx.x >> 6;
    const int tg   = wid & 1;
    const int oh   = wid >> 1;
    const int lrow = lane & 15;
    const int lk   = lane >> 4;
    const int cb   = lk * 8;

    const int n = slot * 32 + tg * 16 + lrow;      // this lane's token

    const float* __restrict__ xb   = x   + (size_t)b * N_PTS * C_CH;
    const int*   __restrict__ adjb = adj + (size_t)b * N_PTS * K_ADJ;
    float*       __restrict__ ob   = out + (size_t)b * C_OUT * N_PTS;

    // center row: 16 channels for this lane's token
    float center[16];
    {
        const float* rp = xb + (size_t)n * C_CH + cb;
        const float4 v0 = *(const float4*)(rp + 0);
        const float4 v1 = *(const float4*)(rp + 4);
        const float4 v2 = *(const float4*)(rp + 32);
        const float4 v3 = *(const float4*)(rp + 36);
        center[0]  = v0.x; center[1]  = v0.y; center[2]  = v0.z; center[3]  = v0.w;
        center[4]  = v1.x; center[5]  = v1.y; center[6]  = v1.z; center[7]  = v1.w;
        center[8]  = v2.x; center[9]  = v2.y; center[10] = v2.z; center[11] = v2.w;
        center[12] = v3.x; center[13] = v3.y; center[14] = v3.z; center[15] = v3.w;
    }

    // all 16 neighbor indices up front (kills the adj->gather serial chain)
    int aidx[N_J];
    {
        const int base = n * K_ADJ + 1;
        #pragma unroll
        for (int j = 0; j < N_J; ++j) aidx[j] = adjb[base + j];
    }

    f32x4 maxacc[4];
    #pragma unroll
    for (int of = 0; of < 4; ++of) maxacc[of] = f32x4{0.f, 0.f, 0.f, 0.f};

    const __hip_bfloat16* __restrict__ wb = g_wb;

    // ---- software pipeline: gather row for j=0 in flight ----
    float4 p0, p1, p2, p3;
    {
        const float* gp = xb + (size_t)aidx[0] * C_CH + cb;
        p0 = *(const float4*)(gp + 0);
        p1 = *(const float4*)(gp + 4);
        p2 = *(const float4*)(gp + 32);
        p3 = *(const float4*)(gp + 36);
    }

    #pragma unroll
    for (int j = 0; j < N_J; ++j) {
        // consume prefetched row -> diff
        float d[16];
        d[0]=p0.x;  d[1]=p0.y;  d[2]=p0.z;  d[3]=p0.w;
        d[4]=p1.x;  d[5]=p1.y;  d[6]=p1.z;  d[7]=p1.w;
        d[8]=p2.x;  d[9]=p2.y;  d[10]=p2.z; d[11]=p2.w;
        d[12]=p3.x; d[13]=p3.y; d[14]=p3.z; d[15]=p3.w;

        // issue next j's gather loads (hidden under this j's VALU+MFMA)
        if (j < N_J - 1) {
            const float* gp = xb + (size_t)aidx[j + 1] * C_CH + cb;
            p0 = *(const float4*)(gp + 0);
            p1 = *(const float4*)(gp + 4);
            p2 = *(const float4*)(gp + 32);
            p3 = *(const float4*)(gp + 36);
        }

        float s = 0.f;
        #pragma unroll
        for (int i = 0; i < 16; ++i) { d[i] -= center[i]; s = fmaf(d[i], d[i], s); }
        // full 64-ch sum: lanes l, l^16, l^32, l^48 share one token
        s += __shfl_xor(s, 16);
        s += __shfl_xor(s, 32);
        // frame normalizer: sqrt(sum(diff^2) + norm^2) = sqrt(2)*norm
        const float scale = rsqrtf(2.0f * s);

        bf16x8 bf0, bf1;
        #pragma unroll
        for (int i = 0; i < 8; ++i) {
            bf0[i] = (short)__builtin_bit_cast(unsigned short, __float2bfloat16(d[i]     * scale));
            bf1[i] = (short)__builtin_bit_cast(unsigned short, __float2bfloat16(d[i + 8] * scale));
        }

        // ---- MFMA: D[o_local][t] = W_j[o][c] * proj[t][c], relu+max folded ----
        const __hip_bfloat16* wj = wb + j * (C_OUT * C_CH);
        #pragma unroll
        for (int of = 0; of < 4; ++of) {
            const __hip_bfloat16* wr = wj + (size_t)(oh * 64 + of * 16 + lrow) * C_CH + cb;
            const bf16x8 a0 = *(const bf16x8*)(wr);        // channels cb+0..7   (k 0..31)
            const bf16x8 a1 = *(const bf16x8*)(wr + 32);   // channels cb+32..39 (k 32..63)
            f32x4 acc = f32x4{0.f, 0.f, 0.f, 0.f};
            acc = __builtin_amdgcn_mfma_f32_16x16x32_bf16(a0, bf0, acc, 0, 0, 0);
            acc = __builtin_amdgcn_mfma_f32_16x16x32_bf16(a1, bf1, acc, 0, 0, 0);
            #pragma unroll
            for (int r = 0; r < 4; ++r)
                maxacc[of][r] = fmaxf(maxacc[of][r], acc[r]);   // relu folded: init 0
        }
    }

    // ---- store: D row = lk*4 + r, col = lane&15 (token) ----
    #pragma unroll
    for (int of = 0; of < 4; ++of) {
        const int o0 = oh * 64 + of * 16 + lk * 4;
        #pragma unroll
        for (int r = 0; r < 4; ++r)
            ob[(size_t)(o0 + r) * N_PTS + n] = maxacc[of][r];
    }
}

extern "C" void kernel_launch(void* const* d_in, const int* in_sizes, int n_in,
                              void* d_out, int out_size, void* d_ws, size_t ws_size,
                              hipStream_t stream) {
    (void)in_sizes; (void)n_in; (void)d_ws; (void)ws_size; (void)out_size;
    const float* x   = (const float*)d_in[0];
    const int*   adj = (const int*)d_in[1];
    const float* w   = (const float*)d_in[2];
    float*       out = (float*)d_out;

    hipLaunchKernelGGL(prep_weights_k, dim3(512),  dim3(256), 0, stream, w);
    hipLaunchKernelGGL(sconv_k,        dim3(1024), dim3(256), 0, stream, x, adj, out);
}

// Round 3
// 99.758 us; speedup vs baseline: 1.3412x; 1.3412x over previous
//
#include <hip/hip_runtime.h>
#include <hip/hip_bf16.h>

typedef __attribute__((ext_vector_type(8))) short bf16x8;
typedef __attribute__((ext_vector_type(4))) float f32x4;

#define N_PTS   16384
#define C_CH    64
#define K_ADJ   17
#define C_OUT   128
#define N_J     16

// bf16 weights, layout [j][o][c] so an A-fragment read is 16B contiguous per lane.
__device__ __hip_bfloat16 g_wb[N_J * C_OUT * C_CH];

__global__ __launch_bounds__(256) void prep_weights_k(const float* __restrict__ w) {
    int idx = blockIdx.x * 256 + threadIdx.x;      // 0 .. 131071 exactly
    int c = idx & 63;
    int o = (idx >> 6) & 127;
    int j = idx >> 13;
    g_wb[idx] = __float2bfloat16(w[(o * C_CH + c) * N_J + j]);
}

// Block: 128 threads = 2 waves. Block tile: 16 tokens x 128 outputs.
// Wave wid = oh (64-output half). Lane l owns token (l&15),
// channels (l>>4)*8 + {0..7} and +32 -> MFMA 16x16x32 B-fragment layout
// (verified round 1: passed, absmax 4.9e-4).
// Per-wave persistent state ~60 VGPRs -> allocator keeps gather loads in
// flight (round 1's 70us was serialized loads from pressure at VGPR=128;
// round 2's forced 64-VGPR cap caused scratch spills, FETCH 31->133MB).
__global__ __launch_bounds__(128) void sconv_k(
    const float* __restrict__ x,
    const int*   __restrict__ adj,
    float*       __restrict__ out)
{
    // XCD-aware bijective swizzle (2048 blocks): batch 0 -> XCDs 0..3,
    // batch 1 -> XCDs 4..7; each XCD's L2 (4 MB) holds its batch's x slice.
    const int p    = blockIdx.x;
    const int g8   = p & 7;
    const int b    = g8 >> 2;                      // batch
    const int slot = ((p >> 3) << 2) | (g8 & 3);   // 0..1023 within batch

    const int lane = threadIdx.x & 63;
    const int oh   = threadIdx.x >> 6;             // 0/1: which 64-output half
    const int lrow = lane & 15;
    const int lk   = lane >> 4;
    const int cb   = lk * 8;

    const int n = slot * 16 + lrow;                // this lane's token

    const float* __restrict__ xb   = x   + (size_t)b * N_PTS * C_CH;
    const int*   __restrict__ adjb = adj + (size_t)b * N_PTS * K_ADJ;
    float*       __restrict__ ob   = out + (size_t)b * C_OUT * N_PTS;

    // center row: 16 channels for this lane's token
    float center[16];
    {
        const float* rp = xb + (size_t)n * C_CH + cb;
        const float4 v0 = *(const float4*)(rp + 0);
        const float4 v1 = *(const float4*)(rp + 4);
        const float4 v2 = *(const float4*)(rp + 32);
        const float4 v3 = *(const float4*)(rp + 36);
        center[0]  = v0.x; center[1]  = v0.y; center[2]  = v0.z; center[3]  = v0.w;
        center[4]  = v1.x; center[5]  = v1.y; center[6]  = v1.z; center[7]  = v1.w;
        center[8]  = v2.x; center[9]  = v2.y; center[10] = v2.z; center[11] = v2.w;
        center[12] = v3.x; center[13] = v3.y; center[14] = v3.z; center[15] = v3.w;
    }

    // all 16 neighbor indices (independent scalar loads, issued in parallel)
    int aidx[N_J];
    {
        const int base = n * K_ADJ + 1;
        #pragma unroll
        for (int j = 0; j < N_J; ++j) aidx[j] = adjb[base + j];
    }

    f32x4 maxacc[4];
    #pragma unroll
    for (int of = 0; of < 4; ++of) maxacc[of] = f32x4{0.f, 0.f, 0.f, 0.f};

    const __hip_bfloat16* __restrict__ wb = g_wb;

    // depth-1 software pipeline: j=0 gather in flight before the loop
    float4 p0, p1, p2, p3;
    {
        const float* gp = xb + (size_t)aidx[0] * C_CH + cb;
        p0 = *(const float4*)(gp + 0);
        p1 = *(const float4*)(gp + 4);
        p2 = *(const float4*)(gp + 32);
        p3 = *(const float4*)(gp + 36);
    }

    #pragma unroll 4
    for (int j = 0; j < N_J; ++j) {
        float d[16];
        d[0]=p0.x;  d[1]=p0.y;  d[2]=p0.z;  d[3]=p0.w;
        d[4]=p1.x;  d[5]=p1.y;  d[6]=p1.z;  d[7]=p1.w;
        d[8]=p2.x;  d[9]=p2.y;  d[10]=p2.z; d[11]=p2.w;
        d[12]=p3.x; d[13]=p3.y; d[14]=p3.z; d[15]=p3.w;

        // issue next j's gather (hides L2/HBM latency under VALU+MFMA below)
        if (j < N_J - 1) {
            const float* gp = xb + (size_t)aidx[j + 1] * C_CH + cb;
            p0 = *(const float4*)(gp + 0);
            p1 = *(const float4*)(gp + 4);
            p2 = *(const float4*)(gp + 32);
            p3 = *(const float4*)(gp + 36);
        }

        float s = 0.f;
        #pragma unroll
        for (int i = 0; i < 16; ++i) { d[i] -= center[i]; s = fmaf(d[i], d[i], s); }
        // full 64-ch sum: lanes l, l^16, l^32, l^48 share one token
        s += __shfl_xor(s, 16);
        s += __shfl_xor(s, 32);
        // frame normalizer: sqrt(sum(diff^2) + norm^2) = sqrt(2)*norm
        const float scale = rsqrtf(2.0f * s);

        bf16x8 bf0, bf1;
        #pragma unroll
        for (int i = 0; i < 8; ++i) {
            bf0[i] = (short)__builtin_bit_cast(unsigned short, __float2bfloat16(d[i]     * scale));
            bf1[i] = (short)__builtin_bit_cast(unsigned short, __float2bfloat16(d[i + 8] * scale));
        }

        // ---- MFMA: D[o_local][t] = W_j[o][c] * proj[t][c], relu+max folded ----
        const __hip_bfloat16* wj = wb + j * (C_OUT * C_CH);
        #pragma unroll
        for (int of = 0; of < 4; ++of) {
            const __hip_bfloat16* wr = wj + (size_t)(oh * 64 + of * 16 + lrow) * C_CH + cb;
            const bf16x8 a0 = *(const bf16x8*)(wr);        // channels cb+0..7   (k 0..31)
            const bf16x8 a1 = *(const bf16x8*)(wr + 32);   // channels cb+32..39 (k 32..63)
            f32x4 acc = f32x4{0.f, 0.f, 0.f, 0.f};
            acc = __builtin_amdgcn_mfma_f32_16x16x32_bf16(a0, bf0, acc, 0, 0, 0);
            acc = __builtin_amdgcn_mfma_f32_16x16x32_bf16(a1, bf1, acc, 0, 0, 0);
            #pragma unroll
            for (int r = 0; r < 4; ++r)
                maxacc[of][r] = fmaxf(maxacc[of][r], acc[r]);   // relu folded: init 0
        }
    }

    // ---- store: D row = lk*4 + r, col = lane&15 (token) ----
    #pragma unroll
    for (int of = 0; of < 4; ++of) {
        const int o0 = oh * 64 + of * 16 + lk * 4;
        #pragma unroll
        for (int r = 0; r < 4; ++r)
            ob[(size_t)(o0 + r) * N_PTS + n] = maxacc[of][r];
    }
}

extern "C" void kernel_launch(void* const* d_in, const int* in_sizes, int n_in,
                              void* d_out, int out_size, void* d_ws, size_t ws_size,
                              hipStream_t stream) {
    (void)in_sizes; (void)n_in; (void)d_ws; (void)ws_size; (void)out_size;
    const float* x   = (const float*)d_in[0];
    const int*   adj = (const int*)d_in[1];
    const float* w   = (const float*)d_in[2];
    float*       out = (float*)d_out;

    hipLaunchKernelGGL(prep_weights_k, dim3(512),  dim3(256), 0, stream, w);
    hipLaunchKernelGGL(sconv_k,        dim3(2048), dim3(128), 0, stream, x, adj, out);
}

// Round 4
// 84.808 us; speedup vs baseline: 1.5777x; 1.1763x over previous
//
#include <hip/hip_runtime.h>
#include <hip/hip_bf16.h>

typedef __attribute__((ext_vector_type(8))) short bf16x8;
typedef __attribute__((ext_vector_type(4))) float f32x4;

#define N_PTS   16384
#define C_CH    64
#define K_ADJ   17
#define C_OUT   128
#define N_J     16

// bf16 weights, layout [j][o][p] where p is the MFMA k-slot. Channel c for
// k-slot p: p = hi*32 + la*8 + r -> c = hi*32 + (r<4 ? la*4+r : 16+la*4+r-4).
// This matches the gather mapping: lane group lk loads 16 contiguous bytes at
// row*256 + i*64 + lk*16 (i=0..3), i.e. channels i*16 + lk*4 + {0..3}.
__device__ __hip_bfloat16 g_wb[N_J * C_OUT * C_CH];

__global__ __launch_bounds__(256) void prep_weights_k(const float* __restrict__ w) {
    int idx = blockIdx.x * 256 + threadIdx.x;      // 0 .. 131071 exactly
    int p = idx & 63;
    int o = (idx >> 6) & 127;
    int j = idx >> 13;
    int hi = p >> 5, q = p & 31, la = q >> 3, r = q & 7;
    int c = hi * 32 + (r < 4 ? la * 4 + r : 16 + la * 4 + (r - 4));
    g_wb[idx] = __float2bfloat16(w[(o * C_CH + c) * (K_ADJ - 1) + j]);
}

// Block: 256 threads = 4 waves = 64 tokens; EACH wave computes all 128 outputs
// for its 16 tokens (no output split -> each gather row fetched once per j).
// Weights staged in LDS in 4-j chunks (64 KB), ds_read_b128 with XOR swizzle.
// Grid 512 = 2 blocks/CU (LDS-limited), single generation.
__global__ __launch_bounds__(256) void sconv_k(
    const float* __restrict__ x,
    const int*   __restrict__ adj,
    float*       __restrict__ out)
{
    __shared__ __hip_bfloat16 lds_w[4 * C_OUT * C_CH];   // 64 KB, swizzled

    // XCD-aware bijective swizzle (512 blocks): batch 0 -> XCDs 0..3,
    // batch 1 -> XCDs 4..7; each XCD's L2 holds its batch's 4 MB x slice.
    const int pblk = blockIdx.x;
    const int g8   = pblk & 7;
    const int b    = g8 >> 2;
    const int slot = ((pblk >> 3) << 2) | (g8 & 3);      // 0..255 within batch

    const int tid  = threadIdx.x;
    const int lane = tid & 63;
    const int wid  = tid >> 6;                            // token group 0..3
    const int lrow = lane & 15;                           // token within group
    const int lk   = lane >> 4;                           // k-slot lane group

    const int n = slot * 64 + wid * 16 + lrow;            // this lane's token

    const float* __restrict__ xb   = x   + (size_t)b * N_PTS * C_CH;
    const int*   __restrict__ adjb = adj + (size_t)b * N_PTS * K_ADJ;
    float*       __restrict__ ob   = out + (size_t)b * C_OUT * N_PTS;

    // center row, remapped gather: 4 x float4, each a full 16B slice of a line
    float ctr[16];
    {
        const float* rp = xb + (size_t)n * C_CH + lk * 4;
        #pragma unroll
        for (int i = 0; i < 4; ++i) {
            float4 v = *(const float4*)(rp + i * 16);
            ctr[i*4+0]=v.x; ctr[i*4+1]=v.y; ctr[i*4+2]=v.z; ctr[i*4+3]=v.w;
        }
    }

    // all 16 neighbor indices up front
    int aidx[N_J];
    {
        const int base = n * K_ADJ + 1;
        #pragma unroll
        for (int j = 0; j < N_J; ++j) aidx[j] = adjb[base + j];
    }

    f32x4 maxacc[8];
    #pragma unroll
    for (int of = 0; of < 8; ++of) maxacc[of] = f32x4{0.f, 0.f, 0.f, 0.f};

    // depth-1 pipeline: j=0 gather in flight (also hides under first LDS fill)
    float4 q0, q1, q2, q3;
    {
        const float* gp = xb + (size_t)aidx[0] * C_CH + lk * 4;
        q0 = *(const float4*)(gp +  0);
        q1 = *(const float4*)(gp + 16);
        q2 = *(const float4*)(gp + 32);
        q3 = *(const float4*)(gp + 48);
    }

    for (int cch = 0; cch < 4; ++cch) {
        if (cch) __syncthreads();                 // readers of prev chunk done
        // ---- fill 64 KB chunk: coalesced global read, swizzled LDS write ----
        const __hip_bfloat16* gw = g_wb + cch * (4 * C_OUT * C_CH);
        #pragma unroll
        for (int it = 0; it < 16; ++it) {
            const int m   = tid + it * 256;       // 16B-chunk index 0..4095
            const bf16x8 v = *(const bf16x8*)(gw + m * 8);
            const int row = m >> 3;               // jj*128 + o
            const int c8s = (m & 7) ^ (row & 7);  // XOR swizzle (T2)
            *(bf16x8*)&lds_w[(row * 8 + c8s) * 8] = v;
        }
        __syncthreads();                          // chunk visible

        #pragma unroll
        for (int jj = 0; jj < 4; ++jj) {
            const int j = cch * 4 + jj;

            float d[16];
            d[0]=q0.x;  d[1]=q0.y;  d[2]=q0.z;  d[3]=q0.w;
            d[4]=q1.x;  d[5]=q1.y;  d[6]=q1.z;  d[7]=q1.w;
            d[8]=q2.x;  d[9]=q2.y;  d[10]=q2.z; d[11]=q2.w;
            d[12]=q3.x; d[13]=q3.y; d[14]=q3.z; d[15]=q3.w;

            // issue next j's gather (hides under VALU + 16 ds_read + 16 MFMA)
            if (j < N_J - 1) {
                const float* gp = xb + (size_t)aidx[j + 1] * C_CH + lk * 4;
                q0 = *(const float4*)(gp +  0);
                q1 = *(const float4*)(gp + 16);
                q2 = *(const float4*)(gp + 32);
                q3 = *(const float4*)(gp + 48);
            }

            float s = 0.f;
            #pragma unroll
            for (int i = 0; i < 16; ++i) { d[i] -= ctr[i]; s = fmaf(d[i], d[i], s); }
            // full 64-ch sum: lanes l, l^16, l^32, l^48 hold disjoint channels
            s += __shfl_xor(s, 16);
            s += __shfl_xor(s, 32);
            // frame normalizer: sqrt(sum(diff^2) + norm^2) = sqrt(2)*norm
            const float scale = rsqrtf(2.0f * s);

            bf16x8 bf0, bf1;
            #pragma unroll
            for (int i = 0; i < 8; ++i) {
                bf0[i] = (short)__builtin_bit_cast(unsigned short, __float2bfloat16(d[i]     * scale));
                bf1[i] = (short)__builtin_bit_cast(unsigned short, __float2bfloat16(d[i + 8] * scale));
            }

            // ---- 8 x (2 MFMA) over all 128 outputs, A-frags from LDS ----
            const int sw = lrow & 7;
            #pragma unroll
            for (int of = 0; of < 8; ++of) {
                const int row = jj * 128 + of * 16 + lrow;
                const bf16x8 a0 = *(const bf16x8*)&lds_w[(row * 8 + ( lk      ^ sw)) * 8];
                const bf16x8 a1 = *(const bf16x8*)&lds_w[(row * 8 + ((4 + lk) ^ sw)) * 8];
                f32x4 acc = f32x4{0.f, 0.f, 0.f, 0.f};
                acc = __builtin_amdgcn_mfma_f32_16x16x32_bf16(a0, bf0, acc, 0, 0, 0);
                acc = __builtin_amdgcn_mfma_f32_16x16x32_bf16(a1, bf1, acc, 0, 0, 0);
                #pragma unroll
                for (int r = 0; r < 4; ++r)
                    maxacc[of][r] = fmaxf(maxacc[of][r], acc[r]);   // relu folded
            }
        }
    }

    // ---- store: D row = lk*4 + r, col = lrow (token) ----
    #pragma unroll
    for (int of = 0; of < 8; ++of) {
        const int o0 = of * 16 + lk * 4;
        #pragma unroll
        for (int r = 0; r < 4; ++r)
            ob[(size_t)(o0 + r) * N_PTS + n] = maxacc[of][r];
    }
}

extern "C" void kernel_launch(void* const* d_in, const int* in_sizes, int n_in,
                              void* d_out, int out_size, void* d_ws, size_t ws_size,
                              hipStream_t stream) {
    (void)in_sizes; (void)n_in; (void)d_ws; (void)ws_size; (void)out_size;
    const float* x   = (const float*)d_in[0];
    const int*   adj = (const int*)d_in[1];
    const float* w   = (const float*)d_in[2];
    float*       out = (float*)d_out;

    hipLaunchKernelGGL(prep_weights_k, dim3(512), dim3(256), 0, stream, w);
    hipLaunchKernelGGL(sconv_k,        dim3(512), dim3(256), 0, stream, x, adj, out);
}